// Round 9
// baseline (80.062 us; speedup 1.0000x reference)
//
#include <hip/hip_runtime.h>
#include <hip/hip_bf16.h>

#define TN 768
#define DIM 768
#define NB 64
#define NA 51
#define POOL 128
#define THRESH 0.75f
#define LNEPS 1e-5f

typedef float f32x4 __attribute__((ext_vector_type(4)));
typedef long l64x2 __attribute__((ext_vector_type(2)));

typedef const __attribute__((address_space(1))) unsigned int* gas_p;
typedef __attribute__((address_space(3))) unsigned int* las_p;

__device__ __forceinline__ void gload16(const void* g, void* l) {
    // dest = lds base + lane*16 (wave-uniform base); src is per-lane
    __builtin_amdgcn_global_load_lds((gas_p)g, (las_p)l, 16, 0, 0);
}

__constant__ int PAIR_I[21] = {0,1,1,2,2,2,3,3,3,3,4,4,4,4,4,5,5,5,5,5,5};
__constant__ int PAIR_J[21] = {0,0,1,0,1,2,0,1,2,3,0,1,2,3,4,0,1,2,3,4,5};

// ---- K1: per-token L2 norm + normalized fp8(e4m3) copy, NATURAL layout ----
// The MFMA k-grouping is an arbitrary partition for a dot product: as long as
// A and B tiles use the same byte->k convention, contiguous granules are
// valid. So xn is stored in plain row order (no permute math, coalesced
// dword stores). Also zeroes bad[] and Lval.
__global__ __launch_bounds__(256) void k_norms(const float* __restrict__ x,
                                               unsigned int* __restrict__ xn,
                                               float* __restrict__ norms,
                                               int* __restrict__ bad,
                                               int* __restrict__ Lval) {
    if (blockIdx.x < 192) bad[blockIdx.x * 256 + threadIdx.x] = 0;
    if (blockIdx.x == 0 && threadIdx.x == 0) *Lval = 0;

    const int tok  = blockIdx.x * 4 + (threadIdx.x >> 6);
    const int lane = threadIdx.x & 63;
    const float4* p = (const float4*)(x + (size_t)tok * DIM);
    float4 v[3];
    float s = 0.f;
#pragma unroll
    for (int q = 0; q < 3; ++q) {
        v[q] = p[q * 64 + lane];
        s += v[q].x * v[q].x + v[q].y * v[q].y + v[q].z * v[q].z + v[q].w * v[q].w;
    }
#pragma unroll
    for (int m = 1; m < 64; m <<= 1) s += __shfl_xor(s, m);
    const float nrm = sqrtf(s);
    const float sc = 1.0f / nrm;
    unsigned int* xrow = xn + (size_t)tok * 192;        // 768 B / 4
#pragma unroll
    for (int q = 0; q < 3; ++q) {
        int w0 = __builtin_amdgcn_cvt_pk_fp8_f32(v[q].x * sc, v[q].y * sc, 0, false);
        w0     = __builtin_amdgcn_cvt_pk_fp8_f32(v[q].z * sc, v[q].w * sc, w0, true);
        xrow[q * 64 + lane] = (unsigned)w0;             // natural position
    }
    if (lane == 0) norms[tok] = nrm;
}

// ---- K2: persistent fp8 gram; 512 blocks (2/CU), 2-3 pairs each, pipeline
//      carried across pair boundaries (stage of next pair's step 0 overlaps
//      last compute + epilogue of current pair). 2-phase dbuf, 64 KB LDS.
struct PS { const unsigned char* pA; const unsigned char* pB; int b, it, jt, diag; };

__global__ __launch_bounds__(256) void k_gram(const unsigned char* __restrict__ xn,
                                              int* __restrict__ bad) {
    const int blk = blockIdx.x;                         // 512 blocks
    // XCD-clustered chunk id: consecutive chunks (same-b pairs) per XCD
    const int chunk = (blk & 7) * 64 + (blk >> 3);
    const int np     = (chunk < 320) ? 3 : 2;           // 320*3 + 192*2 = 1344
    const int pstart = (chunk < 320) ? chunk * 3 : 960 + (chunk - 320) * 2;

    const int tid = threadIdx.x;
    const int lane = tid & 63, w = tid >> 6;
    const int lr = lane & 15, lt = lane >> 4;
    const int wr = w >> 1, wc = w & 1;                  // 2x2 wave grid

    __shared__ alignas(16) unsigned char lA[2][128 * 128];   // 2 x 16 KB
    __shared__ alignas(16) unsigned char lB[2][128 * 128];

    // stage: 1KB LDS segment = 8 rows x 128B; lane l -> row (l>>3), granule
    // (l&7). LDS[row][g] = SRC[row][g ^ (row&7)] (pre-swizzled source, linear
    // dest -- rule #21). Compute reads granule (4q+lt)^(row&7) -> contiguous
    // source bytes [64q+16lt, +16): valid k-grouping (same convention A & B).
    const int srow = lane >> 3;
    const int sgoff = 16 * ((lane & 7) ^ (srow & 7));

    auto mkstate = [&](int idx, PS& s) {
        const int lid = pstart + idx;
        const int b = lid / 21, p = lid - b * 21;
        s.b = b; s.it = PAIR_I[p]; s.jt = PAIR_J[p]; s.diag = (s.it == s.jt);
        const unsigned char* xb = xn + (size_t)b * TN * DIM;
        s.pA = xb + (size_t)(s.jt * 128 + srow) * DIM + sgoff;
        s.pB = xb + (size_t)(s.it * 128 + srow) * DIM + sgoff;
    };

    auto stage = [&](const PS& s, int bb, int kk) {
#pragma unroll
        for (int i = 0; i < 4; ++i) {            // 4 segs/wave = 16 segs = 16 KB
            const int seg = w * 4 + i;
            gload16(s.pA + (size_t)seg * 8 * DIM + kk * 128,
                    (char*)lA[bb] + seg * 1024);
        }
        if (!s.diag) {
#pragma unroll
            for (int i = 0; i < 4; ++i) {
                const int seg = w * 4 + i;
                gload16(s.pB + (size_t)seg * 8 * DIM + kk * 128,
                        (char*)lB[bb] + seg * 1024);
            }
        }
    };

    f32x4 acc[4][4];

    auto compute = [&](int bb, const PS& s) {
        const unsigned char* As = lA[bb];
        const unsigned char* Bs = s.diag ? lA[bb] : lB[bb];
        const int gx = lr & 7;
#pragma unroll
        for (int q = 0; q < 2; ++q) {
            const int goff = 16 * ((4 * q + lt) ^ gx);
            l64x2 a[4], bv[4];
#pragma unroll
            for (int m = 0; m < 4; ++m)
                a[m] = *(const l64x2*)&As[(wr * 64 + m * 16 + lr) * 128 + goff];
#pragma unroll
            for (int n = 0; n < 4; ++n)
                bv[n] = *(const l64x2*)&Bs[(wc * 64 + n * 16 + lr) * 128 + goff];
#pragma unroll
            for (int m = 0; m < 4; ++m)
#pragma unroll
                for (int n = 0; n < 4; ++n) {
                    acc[m][n] = __builtin_amdgcn_mfma_f32_16x16x32_fp8_fp8(a[m][0], bv[n][0], acc[m][n], 0, 0, 0);
                    acc[m][n] = __builtin_amdgcn_mfma_f32_16x16x32_fp8_fp8(a[m][1], bv[n][1], acc[m][n], 0, 0, 0);
                }
        }
    };

    auto epilogue = [&](const PS& s) {
        // C/D layout (dtype-independent): col = lane&15, row = (lane>>4)*4 + reg
#pragma unroll
        for (int m = 0; m < 4; ++m) {
#pragma unroll
            for (int r = 0; r < 4; ++r) {
                const int rowg = s.jt * 128 + wr * 64 + m * 16 + lt * 4 + r;
                bool any = false;
#pragma unroll
                for (int n = 0; n < 4; ++n) {
                    const int colg = s.it * 128 + wc * 64 + n * 16 + lr;
                    any = any || (acc[m][n][r] > THRESH && rowg != colg);
                }
                if (any) bad[s.b * TN + rowg] = 1;   // benign race: all store 1
            }
        }
        if (!s.diag) {   // symmetry: flag columns too
#pragma unroll
            for (int n = 0; n < 4; ++n) {
                const int colg = s.it * 128 + wc * 64 + n * 16 + lr;
                bool any = false;
#pragma unroll
                for (int m = 0; m < 4; ++m)
#pragma unroll
                    for (int r = 0; r < 4; ++r)
                        any = any || (acc[m][n][r] > THRESH);
                if (any) bad[s.b * TN + colg] = 1;
            }
        }
    };

    PS cur, nxt;
    mkstate(0, cur);
    mkstate(1, nxt);                         // np >= 2 always
    stage(cur, 0, 0);
    asm volatile("s_waitcnt vmcnt(0)" ::: "memory");
    __builtin_amdgcn_s_barrier();

    const int total = np * 6;
    for (int i = 0; i < np; ++i) {
#pragma unroll
        for (int m = 0; m < 4; ++m)
#pragma unroll
            for (int n = 0; n < 4; ++n) acc[m][n] = {0.f, 0.f, 0.f, 0.f};
#pragma unroll
        for (int kk = 0; kk < 6; ++kk) {
            const int flat = i * 6 + kk;
            const bool last = (flat == total - 1);
            if (!last) {
                if (kk < 5) stage(cur, (flat + 1) & 1, kk + 1);
                else        stage(nxt, (flat + 1) & 1, 0);
            }
            compute(flat & 1, cur);
            if (!last) {
                asm volatile("s_waitcnt vmcnt(0)" ::: "memory");
                __builtin_amdgcn_s_barrier();
            }
        }
        epilogue(cur);
        if (i + 1 < np) {
            cur = nxt;
            if (i + 2 < np) mkstate(i + 2, nxt);
        }
    }
}

// ---- K3: ballot-based keep/compaction (+ top-k fallback, rank w/ tiebreak) ----
__global__ __launch_bounds__(256) void k_filter(const int* __restrict__ bad,
                                                const float* __restrict__ norms,
                                                int* __restrict__ inv,
                                                int* __restrict__ counts,
                                                int* __restrict__ Lval) {
    const int b = blockIdx.x, t = threadIdx.x;
    const int w = t >> 6, l = t & 63;
    __shared__ unsigned long long kw[12];
    __shared__ float nsh[TN];

    bool kp[3];
#pragma unroll
    for (int q = 0; q < 3; ++q)
        kp[q] = (bad[b * TN + q * 256 + w * 64 + l] == 0);
#pragma unroll
    for (int q = 0; q < 3; ++q) {
        unsigned long long m = __ballot(kp[q]);
        if (l == 0) kw[4 * q + w] = m;
    }
    __syncthreads();
    int total = 0;
    for (int i = 0; i < 12; ++i) total += __popcll(kw[i]);

    if (total < POOL) {
        // fallback: top-128 by norm, ties -> lower index (matches lax.top_k)
        for (int j = t; j < TN; j += 256) nsh[j] = norms[b * TN + j];
        __syncthreads();
#pragma unroll
        for (int q = 0; q < 3; ++q) {
            const int j = q * 256 + w * 64 + l;
            const float nj = nsh[j];
            int rank = 0;
            for (int i = 0; i < TN; ++i) {
                float ni = nsh[i];
                rank += (ni > nj) || (ni == nj && i < j);
            }
            kp[q] = (rank < POOL);
        }
        __syncthreads();          // kw rewrite hazard
#pragma unroll
        for (int q = 0; q < 3; ++q) {
            unsigned long long m = __ballot(kp[q]);
            if (l == 0) kw[4 * q + w] = m;
        }
        __syncthreads();
        total = 0;
        for (int i = 0; i < 12; ++i) total += __popcll(kw[i]);
    }

    // stable scatter via popcount prefix
#pragma unroll
    for (int q = 0; q < 3; ++q) {
        if (kp[q]) {
            const int W = 4 * q + w;
            int pos = __popcll(kw[W] & ((1ull << l) - 1ull));
            for (int i = 0; i < W; ++i) pos += __popcll(kw[i]);
            inv[b * TN + pos] = q * 256 + w * 64 + l;
        }
    }
    if (t == 0) { counts[b] = total; atomicMax(Lval, total); }
}

// ---- K4: pooled row (only a < 51 needed) + LayerNorm + attr head dot ----
// 192 threads (3 waves); thread t owns cols 4t..4t+3; all <=7 row loads
// issued back-to-back (one latency instead of a serial chain).
__device__ inline float block_sum3(float v, volatile float* sred, int t) {
#pragma unroll
    for (int m = 1; m < 64; m <<= 1) v += __shfl_xor(v, m);
    if ((t & 63) == 0) sred[t >> 6] = v;
    __syncthreads();
    float r = sred[0] + sred[1] + sred[2];
    __syncthreads();
    return r;
}

__global__ __launch_bounds__(192) void k_head(const float* __restrict__ x,
                                              const int* __restrict__ inv,
                                              const int* __restrict__ counts,
                                              const int* __restrict__ Lval,
                                              const float* __restrict__ lng,
                                              const float* __restrict__ lnb,
                                              const float* __restrict__ wat,
                                              const float* __restrict__ bat,
                                              float* __restrict__ logits) {
    const int a = blockIdx.x, b = blockIdx.y, t = threadIdx.x;
    __shared__ float sred[3];
    const int L = *Lval, cnt = counts[b];
    const int start = (a * L) >> 7;
    const int end = ((a + 1) * L + 127) >> 7;
    const int wdt = end - start;                 // <= floor(L/128)+1 <= 7
    const int pe = min(end, cnt);
    const int nv = pe - start;                   // block-uniform, 0..7

    int idx[7];
#pragma unroll
    for (int i = 0; i < 7; ++i)
        idx[i] = (i < nv) ? inv[b * TN + start + i] : 0;

    float4 v[7];
#pragma unroll
    for (int i = 0; i < 7; ++i)
        if (i < nv)                              // uniform branch, loads overlap
            v[i] = ((const float4*)(x + (size_t)(b * TN + idx[i]) * DIM))[t];

    float4 s4 = {0.f, 0.f, 0.f, 0.f};
#pragma unroll
    for (int i = 0; i < 7; ++i)
        if (i < nv) {
            s4.x += v[i].x; s4.y += v[i].y; s4.z += v[i].z; s4.w += v[i].w;
        }
    const float iw = 1.0f / (float)wdt;
    s4.x *= iw; s4.y *= iw; s4.z *= iw; s4.w *= iw;

    float s1 = block_sum3(s4.x + s4.y + s4.z + s4.w, sred, t);
    float s2 = block_sum3(s4.x * s4.x + s4.y * s4.y + s4.z * s4.z + s4.w * s4.w, sred, t);
    const float mu = s1 * (1.0f / 768.0f);
    const float var = s2 * (1.0f / 768.0f) - mu * mu;
    const float rstd = rsqrtf(var + LNEPS);

    const float4 g  = ((const float4*)lng)[t];
    const float4 be = ((const float4*)lnb)[t];
    const float4 wv = ((const float4*)(wat + (size_t)a * DIM))[t];
    float d = ((s4.x - mu) * rstd * g.x + be.x) * wv.x
            + ((s4.y - mu) * rstd * g.y + be.y) * wv.y
            + ((s4.z - mu) * rstd * g.z + be.z) * wv.z
            + ((s4.w - mu) * rstd * g.w + be.w) * wv.w;
    float dot = block_sum3(d, sred, t);
    if (t == 0) logits[b * NA + a] = dot + bat[a];
}

// ---------------- K5: BatchNorm1d over batch (training stats) ----------------
__global__ __launch_bounds__(64) void k_bn(const float* __restrict__ logits,
                                           const float* __restrict__ bng,
                                           const float* __restrict__ bnb,
                                           float* __restrict__ out) {
    const int a = threadIdx.x;
    if (a >= NA) return;
    float s = 0.f, s2 = 0.f;
    for (int b = 0; b < NB; ++b) {
        float v = logits[b * NA + a];
        s += v; s2 += v * v;
    }
    const float m = s * (1.0f / 64.0f);
    const float var = s2 * (1.0f / 64.0f) - m * m;
    const float rstd = rsqrtf(var + LNEPS);
    const float ga = bng[a], be = bnb[a];
    for (int b = 0; b < NB; ++b)
        out[b * NA + a] = (logits[b * NA + a] - m) * rstd * ga + be;
}

extern "C" void kernel_launch(void* const* d_in, const int* in_sizes, int n_in,
                              void* d_out, int out_size, void* d_ws, size_t ws_size,
                              hipStream_t stream) {
    const float* x     = (const float*)d_in[0];
    const float* ln_g  = (const float*)d_in[1];
    const float* ln_b  = (const float*)d_in[2];
    const float* w_at  = (const float*)d_in[3];
    const float* b_at  = (const float*)d_in[4];
    const float* bn_g  = (const float*)d_in[5];
    const float* bn_b  = (const float*)d_in[6];
    float* out = (float*)d_out;

    char* wsc = (char*)d_ws;
    const size_t XN = 64ull * 768 * 768;               // 37,748,736 B fp8 copy
    unsigned char* xn = (unsigned char*)wsc;
    float* norms  = (float*)(wsc + XN);                // 196608 B
    int*   bad    = (int*)(wsc + XN + 196608);         // 196608 B
    int*   inv    = (int*)(wsc + XN + 393216);         // 196608 B
    int*   counts = (int*)(wsc + XN + 589824);         // 256 B
    int*   Lval   = (int*)(wsc + XN + 590080);         // 256 B
    float* logits = (float*)(wsc + XN + 590336);       // 13056 B

    k_norms <<<NB * TN / 4, 256, 0, stream>>>(x, (unsigned int*)xn, norms, bad, Lval);
    k_gram  <<<512, 256, 0, stream>>>(xn, bad);
    k_filter<<<NB, 256, 0, stream>>>(bad, norms, inv, counts, Lval);
    k_head  <<<dim3(NA, NB), 192, 0, stream>>>(x, inv, counts, Lval,
                                               ln_g, ln_b, w_at, b_at, logits);
    k_bn    <<<1, 64, 0, stream>>>(logits, bn_g, bn_b, out);
}

// Round 10
// 77.284 us; speedup vs baseline: 1.0359x; 1.0359x over previous
//
#include <hip/hip_runtime.h>
#include <hip/hip_bf16.h>

#define TN 768
#define DIM 768
#define NB 64
#define NA 51
#define POOL 128
#define THRESH 0.75f
#define LNEPS 1e-5f

typedef float f32x4 __attribute__((ext_vector_type(4)));
typedef long l64x2 __attribute__((ext_vector_type(2)));

typedef const __attribute__((address_space(1))) unsigned int* gas_p;
typedef __attribute__((address_space(3))) unsigned int* las_p;

__device__ __forceinline__ void gload16(const void* g, void* l) {
    // dest = lds base + lane*16 (wave-uniform base); src is per-lane
    __builtin_amdgcn_global_load_lds((gas_p)g, (las_p)l, 16, 0, 0);
}

__constant__ int PAIR_I[21] = {0,1,1,2,2,2,3,3,3,3,4,4,4,4,4,5,5,5,5,5,5};
__constant__ int PAIR_J[21] = {0,0,1,0,1,2,0,1,2,3,0,1,2,3,4,0,1,2,3,4,5};

// ---- K1: per-token L2 norm + normalized fp8(e4m3) copy, NATURAL layout ----
// The MFMA k-grouping is an arbitrary partition for a dot product: as long as
// A and B tiles use the same byte->k convention, contiguous granules are
// valid. xn is stored in plain row order (coalesced dword stores).
// Also zeroes bad[] and Lval.
__global__ __launch_bounds__(256) void k_norms(const float* __restrict__ x,
                                               unsigned int* __restrict__ xn,
                                               float* __restrict__ norms,
                                               int* __restrict__ bad,
                                               int* __restrict__ Lval) {
    if (blockIdx.x < 192) bad[blockIdx.x * 256 + threadIdx.x] = 0;
    if (blockIdx.x == 0 && threadIdx.x == 0) *Lval = 0;

    const int tok  = blockIdx.x * 4 + (threadIdx.x >> 6);
    const int lane = threadIdx.x & 63;
    const float4* p = (const float4*)(x + (size_t)tok * DIM);
    float4 v[3];
    float s = 0.f;
#pragma unroll
    for (int q = 0; q < 3; ++q) {
        v[q] = p[q * 64 + lane];
        s += v[q].x * v[q].x + v[q].y * v[q].y + v[q].z * v[q].z + v[q].w * v[q].w;
    }
#pragma unroll
    for (int m = 1; m < 64; m <<= 1) s += __shfl_xor(s, m);
    const float nrm = sqrtf(s);
    const float sc = 1.0f / nrm;
    unsigned int* xrow = xn + (size_t)tok * 192;        // 768 B / 4
#pragma unroll
    for (int q = 0; q < 3; ++q) {
        int w0 = __builtin_amdgcn_cvt_pk_fp8_f32(v[q].x * sc, v[q].y * sc, 0, false);
        w0     = __builtin_amdgcn_cvt_pk_fp8_f32(v[q].z * sc, v[q].w * sc, w0, true);
        xrow[q * 64 + lane] = (unsigned)w0;             // natural position
    }
    if (lane == 0) norms[tok] = nrm;
}

// ---- K2: fp8 gram tiles, triangle (21 pairs), 2-phase dbuf, 64x64 wave tiles ----
// Round-8-proven structure: 1344 blocks (fluid dispatch), 256 thr (2x2 wave
// grid), 64 KB LDS (2 blocks/CU), 6 K-steps of 128 fp8.
__global__ __launch_bounds__(256) void k_gram(const unsigned char* __restrict__ xn,
                                              int* __restrict__ bad) {
    // bijective XCD swizzle: 1344 blocks = 8 XCD x 168
    const int f = blockIdx.x;
    const int lid = (f & 7) * 168 + (f >> 3);
    const int b = lid / 21, p = lid - b * 21;
    const int it = PAIR_I[p], jt = PAIR_J[p];
    const bool diag = (it == jt);

    const int tid = threadIdx.x;
    const int lane = tid & 63, w = tid >> 6;
    const int lr = lane & 15, lt = lane >> 4;
    const int wr = w >> 1, wc = w & 1;                  // 2x2 wave grid

    __shared__ alignas(16) unsigned char lA[2][128 * 128];   // 2 x 16 KB
    __shared__ alignas(16) unsigned char lB[2][128 * 128];

    const unsigned char* xb = xn + (size_t)b * TN * DIM;     // 768 B / token
    // stage: 1KB LDS segment = 8 rows x 128B; lane l -> row (l>>3), granule
    // (l&7). LDS[row][g] = SRC[row][g ^ (row&7)] (pre-swizzled source, linear
    // dest -- rule #21). Compute reads granule (4q+lt)^(row&7) -> contiguous
    // source bytes [64q+16lt, +16): valid k-grouping (same convention A & B).
    const int srow = lane >> 3;
    const int sgoff = 16 * ((lane & 7) ^ (srow & 7));
    const size_t baseA = (size_t)(jt * 128 + srow) * DIM + sgoff;
    const size_t baseB = (size_t)(it * 128 + srow) * DIM + sgoff;

    f32x4 acc[4][4];
#pragma unroll
    for (int m = 0; m < 4; ++m)
#pragma unroll
        for (int n = 0; n < 4; ++n) acc[m][n] = {0.f, 0.f, 0.f, 0.f};

    auto stage = [&](int bb, int kk) {
#pragma unroll
        for (int i = 0; i < 4; ++i) {            // 4 segs/wave = 16 segs = 16 KB
            const int seg = w * 4 + i;
            gload16(xb + baseA + (size_t)seg * 8 * DIM + kk * 128,
                    (char*)lA[bb] + seg * 1024);
        }
        if (!diag) {
#pragma unroll
            for (int i = 0; i < 4; ++i) {
                const int seg = w * 4 + i;
                gload16(xb + baseB + (size_t)seg * 8 * DIM + kk * 128,
                        (char*)lB[bb] + seg * 1024);
            }
        }
    };

    auto compute = [&](int bb) {
        const unsigned char* As = lA[bb];
        const unsigned char* Bs = diag ? lA[bb] : lB[bb];
        const int gx = lr & 7;
#pragma unroll
        for (int q = 0; q < 2; ++q) {
            const int goff = 16 * ((4 * q + lt) ^ gx);
            l64x2 a[4], bv[4];
#pragma unroll
            for (int m = 0; m < 4; ++m)
                a[m] = *(const l64x2*)&As[(wr * 64 + m * 16 + lr) * 128 + goff];
#pragma unroll
            for (int n = 0; n < 4; ++n)
                bv[n] = *(const l64x2*)&Bs[(wc * 64 + n * 16 + lr) * 128 + goff];
#pragma unroll
            for (int m = 0; m < 4; ++m)
#pragma unroll
                for (int n = 0; n < 4; ++n) {
                    acc[m][n] = __builtin_amdgcn_mfma_f32_16x16x32_fp8_fp8(a[m][0], bv[n][0], acc[m][n], 0, 0, 0);
                    acc[m][n] = __builtin_amdgcn_mfma_f32_16x16x32_fp8_fp8(a[m][1], bv[n][1], acc[m][n], 0, 0, 0);
                }
        }
    };

    // 2-phase pipeline: stage(next) || compute(cur); one vmcnt(0)+barrier/step
    stage(0, 0);
    asm volatile("s_waitcnt vmcnt(0)" ::: "memory");
    __builtin_amdgcn_s_barrier();
#pragma unroll
    for (int kk = 0; kk < 6; ++kk) {
        const int cur = kk & 1;
        if (kk < 5) stage(cur ^ 1, kk + 1);
        compute(cur);
        if (kk < 5) {
            asm volatile("s_waitcnt vmcnt(0)" ::: "memory");
            __builtin_amdgcn_s_barrier();
        }
    }

    // C/D layout (dtype-independent): col = lane&15, row = (lane>>4)*4 + reg
#pragma unroll
    for (int m = 0; m < 4; ++m) {
#pragma unroll
        for (int r = 0; r < 4; ++r) {
            const int rowg = jt * 128 + wr * 64 + m * 16 + lt * 4 + r;
            bool any = false;
#pragma unroll
            for (int n = 0; n < 4; ++n) {
                const int colg = it * 128 + wc * 64 + n * 16 + lr;
                any = any || (acc[m][n][r] > THRESH && rowg != colg);
            }
            if (any) bad[b * TN + rowg] = 1;   // benign race: all writers store 1
        }
    }
    if (!diag) {   // symmetry: flag columns too (their row view is this tile^T)
#pragma unroll
        for (int n = 0; n < 4; ++n) {
            const int colg = it * 128 + wc * 64 + n * 16 + lr;
            bool any = false;
#pragma unroll
            for (int m = 0; m < 4; ++m)
#pragma unroll
                for (int r = 0; r < 4; ++r)
                    any = any || (acc[m][n][r] > THRESH);
            if (any) bad[b * TN + colg] = 1;
        }
    }
}

// ---- K3: ballot-based keep/compaction (+ top-k fallback, rank w/ tiebreak) ----
__global__ __launch_bounds__(256) void k_filter(const int* __restrict__ bad,
                                                const float* __restrict__ norms,
                                                int* __restrict__ inv,
                                                int* __restrict__ counts,
                                                int* __restrict__ Lval) {
    const int b = blockIdx.x, t = threadIdx.x;
    const int w = t >> 6, l = t & 63;
    __shared__ unsigned long long kw[12];
    __shared__ float nsh[TN];

    bool kp[3];
#pragma unroll
    for (int q = 0; q < 3; ++q)
        kp[q] = (bad[b * TN + q * 256 + w * 64 + l] == 0);
#pragma unroll
    for (int q = 0; q < 3; ++q) {
        unsigned long long m = __ballot(kp[q]);
        if (l == 0) kw[4 * q + w] = m;
    }
    __syncthreads();
    int total = 0;
    for (int i = 0; i < 12; ++i) total += __popcll(kw[i]);

    if (total < POOL) {
        // fallback: top-128 by norm, ties -> lower index (matches lax.top_k)
        for (int j = t; j < TN; j += 256) nsh[j] = norms[b * TN + j];
        __syncthreads();
#pragma unroll
        for (int q = 0; q < 3; ++q) {
            const int j = q * 256 + w * 64 + l;
            const float nj = nsh[j];
            int rank = 0;
            for (int i = 0; i < TN; ++i) {
                float ni = nsh[i];
                rank += (ni > nj) || (ni == nj && i < j);
            }
            kp[q] = (rank < POOL);
        }
        __syncthreads();          // kw rewrite hazard
#pragma unroll
        for (int q = 0; q < 3; ++q) {
            unsigned long long m = __ballot(kp[q]);
            if (l == 0) kw[4 * q + w] = m;
        }
        __syncthreads();
        total = 0;
        for (int i = 0; i < 12; ++i) total += __popcll(kw[i]);
    }

    // stable scatter via popcount prefix
#pragma unroll
    for (int q = 0; q < 3; ++q) {
        if (kp[q]) {
            const int W = 4 * q + w;
            int pos = __popcll(kw[W] & ((1ull << l) - 1ull));
            for (int i = 0; i < W; ++i) pos += __popcll(kw[i]);
            inv[b * TN + pos] = q * 256 + w * 64 + l;
        }
    }
    if (t == 0) { counts[b] = total; atomicMax(Lval, total); }
}

// ---- K4: pooled row (only a < 51 needed) + LayerNorm + attr head dot ----
// 192 threads (3 waves); thread t owns cols 4t..4t+3; all <=7 row loads
// issued back-to-back (one latency instead of a serial chain).
__device__ inline float block_sum3(float v, volatile float* sred, int t) {
#pragma unroll
    for (int m = 1; m < 64; m <<= 1) v += __shfl_xor(v, m);
    if ((t & 63) == 0) sred[t >> 6] = v;
    __syncthreads();
    float r = sred[0] + sred[1] + sred[2];
    __syncthreads();
    return r;
}

__global__ __launch_bounds__(192) void k_head(const float* __restrict__ x,
                                              const int* __restrict__ inv,
                                              const int* __restrict__ counts,
                                              const int* __restrict__ Lval,
                                              const float* __restrict__ lng,
                                              const float* __restrict__ lnb,
                                              const float* __restrict__ wat,
                                              const float* __restrict__ bat,
                                              float* __restrict__ logits) {
    const int a = blockIdx.x, b = blockIdx.y, t = threadIdx.x;
    __shared__ float sred[3];
    const int L = *Lval, cnt = counts[b];
    const int start = (a * L) >> 7;
    const int end = ((a + 1) * L + 127) >> 7;
    const int wdt = end - start;                 // <= floor(L/128)+1 <= 7
    const int pe = min(end, cnt);
    const int nv = pe - start;                   // block-uniform, 0..7

    int idx[7];
#pragma unroll
    for (int i = 0; i < 7; ++i)
        idx[i] = (i < nv) ? inv[b * TN + start + i] : 0;

    float4 v[7];
#pragma unroll
    for (int i = 0; i < 7; ++i)
        if (i < nv)                              // uniform branch, loads overlap
            v[i] = ((const float4*)(x + (size_t)(b * TN + idx[i]) * DIM))[t];

    float4 s4 = {0.f, 0.f, 0.f, 0.f};
#pragma unroll
    for (int i = 0; i < 7; ++i)
        if (i < nv) {
            s4.x += v[i].x; s4.y += v[i].y; s4.z += v[i].z; s4.w += v[i].w;
        }
    const float iw = 1.0f / (float)wdt;
    s4.x *= iw; s4.y *= iw; s4.z *= iw; s4.w *= iw;

    float s1 = block_sum3(s4.x + s4.y + s4.z + s4.w, sred, t);
    float s2 = block_sum3(s4.x * s4.x + s4.y * s4.y + s4.z * s4.z + s4.w * s4.w, sred, t);
    const float mu = s1 * (1.0f / 768.0f);
    const float var = s2 * (1.0f / 768.0f) - mu * mu;
    const float rstd = rsqrtf(var + LNEPS);

    const float4 g  = ((const float4*)lng)[t];
    const float4 be = ((const float4*)lnb)[t];
    const float4 wv = ((const float4*)(wat + (size_t)a * DIM))[t];
    float d = ((s4.x - mu) * rstd * g.x + be.x) * wv.x
            + ((s4.y - mu) * rstd * g.y + be.y) * wv.y
            + ((s4.z - mu) * rstd * g.z + be.z) * wv.z
            + ((s4.w - mu) * rstd * g.w + be.w) * wv.w;
    float dot = block_sum3(d, sred, t);
    if (t == 0) logits[b * NA + a] = dot + bat[a];
}

// ---------------- K5: BatchNorm1d over batch (training stats) ----------------
__global__ __launch_bounds__(64) void k_bn(const float* __restrict__ logits,
                                           const float* __restrict__ bng,
                                           const float* __restrict__ bnb,
                                           float* __restrict__ out) {
    const int a = threadIdx.x;
    if (a >= NA) return;
    float s = 0.f, s2 = 0.f;
    for (int b = 0; b < NB; ++b) {
        float v = logits[b * NA + a];
        s += v; s2 += v * v;
    }
    const float m = s * (1.0f / 64.0f);
    const float var = s2 * (1.0f / 64.0f) - m * m;
    const float rstd = rsqrtf(var + LNEPS);
    const float ga = bng[a], be = bnb[a];
    for (int b = 0; b < NB; ++b)
        out[b * NA + a] = (logits[b * NA + a] - m) * rstd * ga + be;
}

extern "C" void kernel_launch(void* const* d_in, const int* in_sizes, int n_in,
                              void* d_out, int out_size, void* d_ws, size_t ws_size,
                              hipStream_t stream) {
    const float* x     = (const float*)d_in[0];
    const float* ln_g  = (const float*)d_in[1];
    const float* ln_b  = (const float*)d_in[2];
    const float* w_at  = (const float*)d_in[3];
    const float* b_at  = (const float*)d_in[4];
    const float* bn_g  = (const float*)d_in[5];
    const float* bn_b  = (const float*)d_in[6];
    float* out = (float*)d_out;

    char* wsc = (char*)d_ws;
    const size_t XN = 64ull * 768 * 768;               // 37,748,736 B fp8 copy
    unsigned char* xn = (unsigned char*)wsc;
    float* norms  = (float*)(wsc + XN);                // 196608 B
    int*   bad    = (int*)(wsc + XN + 196608);         // 196608 B
    int*   inv    = (int*)(wsc + XN + 393216);         // 196608 B
    int*   counts = (int*)(wsc + XN + 589824);         // 256 B
    int*   Lval   = (int*)(wsc + XN + 590080);         // 256 B
    float* logits = (float*)(wsc + XN + 590336);       // 13056 B

    k_norms <<<NB * TN / 4, 256, 0, stream>>>(x, (unsigned int*)xn, norms, bad, Lval);
    k_gram  <<<21 * NB, 256, 0, stream>>>(xn, bad);
    k_filter<<<NB, 256, 0, stream>>>(bad, norms, inv, counts, Lval);
    k_head  <<<dim3(NA, NB), 192, 0, stream>>>(x, inv, counts, Lval,
                                               ln_g, ln_b, w_at, b_at, logits);
    k_bn    <<<1, 64, 0, stream>>>(logits, bn_g, bn_b, out);
}